// Round 1
// 64.844 us; speedup vs baseline: 1.0747x; 1.0747x over previous
//
#include <hip/hip_runtime.h>

#define IH 256
#define IW 256
#define NK 512
#define ZTH 3.0f
#define EPSV 1e-8f
// Row-level cull: rowfac = w * exp(-0.5*dxn^2) bounds every alpha this
// gaussian can produce on this row. Culling at 1e-10 perturbs the output
// by < ~64*1e-10 ≈ 6e-8 absolute — below the harness tolerance headroom
// (previous kernel passed at absmax 3e-8 with NO culling).
#define RFCULL 1e-10f

// One fused kernel, block = image row (256 blocks, 256 threads).
// v2: per-row gaussian culling. A gaussian with s_x<=5 only touches
// ~|y-px| < 6.8*s_x ≈ 41 of 256 rows, so of the ~60 z-active gaussians
// only ~10 matter for any given row. Cull during compaction (rowfac needs
// only blockIdx.x), so BOTH the O(m^2) rank loop (60^2 -> ~10^2) and the
// per-pixel composite loop (64 -> ~12 iters of ds_read_b128 + v_exp chain)
// shrink ~5-30x. Compaction is wave-ballot segmented (no LDS atomic, no
// init barrier): 2 barriers total.
__launch_bounds__(256, 4)
__global__ void slice_render_fused(const float* __restrict__ positions,
                                   const float* __restrict__ scales,
                                   const float* __restrict__ opacity,
                                   const float* __restrict__ intensity,
                                   const float* __restrict__ z_target,
                                   float* __restrict__ out) {
    // Segment s (one per wave) holds its survivors at [s*128, s*128+cnt).
    __shared__ unsigned long long s_key[NK];   // (w_bits<<32)|(NK-1-idx): sort key
    __shared__ float4 s_g[NK];                 // {py, 1/sy, rowfac, intensity}
    __shared__ float4 s_srt[NK + 4];           // rank-ordered survivors + pad
    __shared__ int    s_scnt[4];

    const int tid  = threadIdx.x;
    const int lane = tid & 63;
    const int wid  = tid >> 6;
    const float zt = z_target[0];
    const float y  = (float)blockIdx.x;
    const unsigned long long ltmask = (1ull << lane) - 1ull;

    // ---- compaction + per-row cull (wave-segmented, no atomics) ----
    int base = 0;
    for (int r = 0; r < 2; ++r) {
        const int k = tid + 256 * r;
        float w = 0.0f, rowfac = 0.0f, py = 0.0f, isy = 1.0f, inten = 0.0f;
        bool keep = false;
        {
            float zd = (zt - positions[3 * k + 2]) / (scales[3 * k + 2] + EPSV);
            if (fabsf(zd) < ZTH) {
                w = opacity[k] * __expf(-0.5f * zd * zd);
                if (w > 0.0f) {
                    float isx = 1.0f / (scales[3 * k + 0] + EPSV);
                    float dx  = (y - positions[3 * k + 0]) * isx;
                    rowfac = w * __expf(-0.5f * dx * dx);
                    if (rowfac >= RFCULL) {
                        keep  = true;
                        py    = positions[3 * k + 1];
                        isy   = 1.0f / (scales[3 * k + 1] + EPSV);
                        inten = intensity[k];
                    }
                }
            }
        }
        unsigned long long mask = __ballot(keep);
        if (keep) {
            int slot = wid * 128 + base + (int)__popcll(mask & ltmask);
            // w > 0 so IEEE bit pattern orders like the float; tie-break by
            // ascending original idx == stable argsort(-eff_w) on survivors.
            s_key[slot] = ((unsigned long long)__float_as_uint(w) << 32)
                          | (unsigned int)(NK - 1 - k);
            s_g[slot] = make_float4(py, isy, rowfac, inten);
        }
        base += (int)__popcll(mask);
    }
    if (lane == 0) s_scnt[wid] = base;
    __syncthreads();

    const int c0 = s_scnt[0], c1 = s_scnt[1], c2 = s_scnt[2], c3 = s_scnt[3];
    const int m  = c0 + c1 + c2 + c3;
    const int mp = (m + 3) & ~3;

    // ---- rank sort (~10 survivors) + scatter; pure LDS broadcasts ----
    for (int t = tid; t < NK; t += 256) {
        const int seg = t >> 7, i = t & 127;
        const int cseg = (seg == 0) ? c0 : (seg == 1) ? c1 : (seg == 2) ? c2 : c3;
        if (i < cseg) {
            const unsigned long long ki = s_key[t];
            int rank = 0;
            for (int j = 0; j < c0; ++j) rank += (s_key[      j] > ki) ? 1 : 0;
            for (int j = 0; j < c1; ++j) rank += (s_key[128 + j] > ki) ? 1 : 0;
            for (int j = 0; j < c2; ++j) rank += (s_key[256 + j] > ki) ? 1 : 0;
            for (int j = 0; j < c3; ++j) rank += (s_key[384 + j] > ki) ? 1 : 0;
            s_srt[rank] = s_g[t];
        }
    }
    for (int i = m + tid; i < mp; i += 256)
        s_srt[i] = make_float4(0.0f, 1.0f, 0.0f, 0.0f);   // alpha == 0 pad
    __syncthreads();

    // ---- per-pixel front-to-back compositing over ~12 survivors ----
    const float x = (float)tid;
    float T = 1.0f, acc = 0.0f;
    for (int k0 = 0; k0 < mp; k0 += 4) {
#pragma unroll
        for (int u = 0; u < 4; ++u) {
            float4 g = s_srt[k0 + u];            // uniform ds_read_b128 broadcast
            float dy = (x - g.x) * g.y;
            float a  = fminf(__expf(-0.5f * dy * dy) * g.z, 0.99f);
            acc += T * a * g.w;
            T   *= 1.0f - a;
        }
    }
    out[blockIdx.x * IW + tid] = acc;
}

extern "C" void kernel_launch(void* const* d_in, const int* in_sizes, int n_in,
                              void* d_out, int out_size, void* d_ws, size_t ws_size,
                              hipStream_t stream) {
    (void)in_sizes; (void)n_in; (void)out_size; (void)d_ws; (void)ws_size;
    const float* positions = (const float*)d_in[0];
    const float* scales    = (const float*)d_in[1];
    const float* opacity   = (const float*)d_in[2];
    const float* intensity = (const float*)d_in[3];
    const float* z_target  = (const float*)d_in[4];
    float* out = (float*)d_out;
    hipLaunchKernelGGL(slice_render_fused, dim3(IH), dim3(256), 0, stream,
                       positions, scales, opacity, intensity, z_target, out);
}